// Round 2
// baseline (2105.151 us; speedup 1.0000x reference)
//
#include <hip/hip_runtime.h>
#include <hip/hip_bf16.h>

// SSA attention, B=1 S=4096 HID=4096 H=32 KV=8 D=128.
// R2: dtype-robust. Detect fp32-vs-bf16 inputs at runtime; convert to bf16
// during GEMM LDS staging (B transposed in staging). Intermediates bf16.

typedef short bf16x8 __attribute__((ext_vector_type(8)));
typedef float f32x4 __attribute__((ext_vector_type(4)));
using bf16 = __hip_bfloat16;

#define S_LEN 4096
#define HIDN  4096
#define NH    32
#define NKV   8
#define DH    128
#define NBLK  64
#define SCALE 0.08838834764831845f

// ---------------- dtype detector ----------------
// Reads first 256 u16 of wq. True bf16 N(0,0.02) data: exponent ~<=123,
// zero "bad". fp32 data read as u16: every even u16 is a float's low
// mantissa half -> bf16-exponent uniform -> ~47% have e>=134 (|x|>=128
// or NaN/Inf). flag=1 means inputs are fp32.
__global__ void k_detect(const unsigned short* __restrict__ w,
                         int* __restrict__ flag) {
  int t = threadIdx.x;
  unsigned short u = w[t];
  int e = (u >> 7) & 0xFF;
  int bad = (e >= 134) ? 1 : 0;
  __shared__ int cnt;
  if (t == 0) cnt = 0;
  __syncthreads();
  atomicAdd(&cnt, bad);
  __syncthreads();
  if (t == 0) flag[0] = (cnt > 32) ? 1 : 0;
}

// ---------------- GEMM: C[M][N] = A[M][K] * B[K][N] ----------------
// A,B global dtype: bf16, or fp32 when (mode && *flagp). B transposed to
// [n][k] during LDS staging. outMode: 0 = bf16 store, 1 = fp32 when flag.
__global__ __launch_bounds__(256) void k_gemm(
    const void* __restrict__ A_, const void* __restrict__ B_,
    void* __restrict__ C_, const int* __restrict__ flagp,
    int M, int N, int K, int aMode, int bMode, int outMode) {
  __shared__ bf16 Al[128][72];
  __shared__ bf16 Bl[128][72];
  const int flag = *flagp;
  const bool aF32 = aMode && flag;
  const bool bF32 = bMode && flag;
  const int m0 = blockIdx.x * 128, n0 = blockIdx.y * 128;
  const int t = threadIdx.x;
  const int wid = t >> 6, lane = t & 63, quad = lane >> 4, l16 = lane & 15;
  const int wr = (wid >> 1) * 64, wc = (wid & 1) * 64;
  f32x4 acc[4][4] = {};
  const int srow = t >> 3, skoff = (t & 7) * 8;  // A staging
  const int tk = t >> 4, tn8 = (t & 15) * 8;     // B staging

  for (int kb = 0; kb < K; kb += 64) {
    // ---- A tile [128 m][64 k] -> Al[m][k]
#pragma unroll
    for (int p = 0; p < 4; p++) {
      int row = p * 32 + srow;
      if (!aF32) {
        *(uint4*)(&Al[row][skoff]) =
            *(const uint4*)((const bf16*)A_ + (size_t)(m0 + row) * K + kb + skoff);
      } else {
        const float* Af = (const float*)A_ + (size_t)(m0 + row) * K + kb + skoff;
        float4 f0 = *(const float4*)Af;
        float4 f1 = *(const float4*)(Af + 4);
        alignas(16) bf16 tmp[8] = {
            __float2bfloat16(f0.x), __float2bfloat16(f0.y),
            __float2bfloat16(f0.z), __float2bfloat16(f0.w),
            __float2bfloat16(f1.x), __float2bfloat16(f1.y),
            __float2bfloat16(f1.z), __float2bfloat16(f1.w)};
        *(uint4*)(&Al[row][skoff]) = *(const uint4*)tmp;
      }
    }
    // ---- B tile [64 k][128 n] -> Bl[n][k] (transpose in staging)
#pragma unroll
    for (int p = 0; p < 4; p++) {
      int k = p * 16 + tk;
      alignas(16) bf16 vals[8];
      if (!bF32) {
        *(uint4*)vals =
            *(const uint4*)((const bf16*)B_ + (size_t)(kb + k) * N + n0 + tn8);
      } else {
        const float* Bf = (const float*)B_ + (size_t)(kb + k) * N + n0 + tn8;
        float4 f0 = *(const float4*)Bf;
        float4 f1 = *(const float4*)(Bf + 4);
        vals[0] = __float2bfloat16(f0.x); vals[1] = __float2bfloat16(f0.y);
        vals[2] = __float2bfloat16(f0.z); vals[3] = __float2bfloat16(f0.w);
        vals[4] = __float2bfloat16(f1.x); vals[5] = __float2bfloat16(f1.y);
        vals[6] = __float2bfloat16(f1.z); vals[7] = __float2bfloat16(f1.w);
      }
#pragma unroll
      for (int jj = 0; jj < 8; jj++) Bl[tn8 + jj][k] = vals[jj];
    }
    __syncthreads();
#pragma unroll
    for (int kk = 0; kk < 64; kk += 32) {
      bf16x8 af[4], bfr[4];
#pragma unroll
      for (int i = 0; i < 4; i++)
        af[i] = *(const bf16x8*)(&Al[wr + i * 16 + l16][kk + quad * 8]);
#pragma unroll
      for (int i = 0; i < 4; i++)
        bfr[i] = *(const bf16x8*)(&Bl[wc + i * 16 + l16][kk + quad * 8]);
#pragma unroll
      for (int mt = 0; mt < 4; mt++)
#pragma unroll
        for (int nt = 0; nt < 4; nt++)
          acc[mt][nt] = __builtin_amdgcn_mfma_f32_16x16x32_bf16(
              af[mt], bfr[nt], acc[mt][nt], 0, 0, 0);
    }
    __syncthreads();
  }
  const bool storeF32 = outMode && flag;
#pragma unroll
  for (int mt = 0; mt < 4; mt++)
#pragma unroll
    for (int nt = 0; nt < 4; nt++)
#pragma unroll
      for (int r = 0; r < 4; r++) {
        int m = m0 + wr + mt * 16 + quad * 4 + r;
        int n = n0 + wc + nt * 16 + l16;
        float v = acc[mt][nt][r];
        if (storeF32)
          ((float*)C_)[(size_t)m * N + n] = v;
        else
          ((bf16*)C_)[(size_t)m * N + n] = __float2bfloat16(v);
      }
}

// ---------------- RoPE in place on [S][nheads*DH] (bf16) ----------------
__global__ void k_rope(bf16* __restrict__ x, int nheads, int total) {
  int idx = blockIdx.x * blockDim.x + threadIdx.x;
  if (idx >= total) return;
  int j = idx & 63;   // freq index
  int sh = idx >> 6;  // s*nheads + head
  int s = sh / nheads;
  float invf = (float)exp(-(double)j * (9.210340371976184 / 64.0));
  float ang = (float)s * invf;
  float sn, cs;
  sincosf(ang, &sn, &cs);
  bf16* p = x + (size_t)sh * DH;
  float x1 = __bfloat162float(p[j]);
  float x2 = __bfloat162float(p[j + 64]);
  p[j]      = __float2bfloat16(x1 * cs - x2 * sn);
  p[j + 64] = __float2bfloat16(x2 * cs + x1 * sn);
}

// ---------------- attention: one block per (query-block nb, head h) ------
// local: causal window [q-64, q] (block-0 zero-pad keys included, score 0)
// landmark: landmarks 0..nb (positions 64*l), separate softmax, 0.7/0.3 mix
__global__ __launch_bounds__(256) void k_attn(const bf16* __restrict__ Q,
                                              const bf16* __restrict__ Kk,
                                              const bf16* __restrict__ V,
                                              bf16* __restrict__ O) {
  const int nb = blockIdx.x;
  const int h = blockIdx.y;
  const int kvh = h >> 2;
  const int t = threadIdx.x;
  const int wid = t >> 6, lane = t & 63, quad = lane >> 4, l16 = lane & 15;

  __shared__ bf16 Qs[64 * 136];   // Q tile; reused as P (exp weights)
  __shared__ bf16 kvb[128 * 136]; // K chunks [64][136] / Vt,LVt [128][72]
  __shared__ bf16 PLs[64 * 72];   // landmark exp weights

  const int srow16 = t >> 4, soff = (t & 15) * 8;

  // stage Q [64][128] -> Qs stride 136
#pragma unroll
  for (int p = 0; p < 4; p++) {
    int row = p * 16 + srow16;
    *(uint4*)(&Qs[row * 136 + soff]) =
        *(const uint4*)(Q + ((size_t)(nb * 64 + row) * NH + h) * DH + soff);
  }

  auto stageK = [&](int basePos, int posStride) {
#pragma unroll
    for (int p = 0; p < 4; p++) {
      int row = p * 16 + srow16;
      int pos = basePos + row * posStride;
      uint4 val = make_uint4(0u, 0u, 0u, 0u);
      if (pos >= 0)
        val = *(const uint4*)(Kk + ((size_t)pos * NKV + kvh) * DH + soff);
      *(uint4*)(&kvb[row * 136 + soff]) = val;
    }
  };

  auto stageVt = [&](int basePos, int posStride) {
#pragma unroll
    for (int p = 0; p < 4; p++) {
      int key = p * 16 + srow16;
      int pos = basePos + key * posStride;
      uint4 tv = make_uint4(0u, 0u, 0u, 0u);
      if (pos >= 0)
        tv = *(const uint4*)(V + ((size_t)pos * NKV + kvh) * DH + soff);
      const bf16* tmp = (const bf16*)&tv;
#pragma unroll
      for (int jj = 0; jj < 8; jj++)
        kvb[(soff + jj) * 72 + key] = tmp[jj];
    }
  };

  f32x4 sc[8] = {};
  f32x4 slm[4] = {};

  auto scoreStep = [&](f32x4* dst) {
#pragma unroll
    for (int kk = 0; kk < 128; kk += 32) {
      bf16x8 a = *(const bf16x8*)(&Qs[(wid * 16 + l16) * 136 + kk + quad * 8]);
#pragma unroll
      for (int nt = 0; nt < 4; nt++) {
        bf16x8 b =
            *(const bf16x8*)(&kvb[(nt * 16 + l16) * 136 + kk + quad * 8]);
        dst[nt] = __builtin_amdgcn_mfma_f32_16x16x32_bf16(a, b, dst[nt], 0, 0, 0);
      }
    }
  };

  stageK(nb * 64 - 64, 1);  // keys [nb*64-64, nb*64)
  __syncthreads();
  scoreStep(&sc[0]);
  __syncthreads();
  stageK(nb * 64, 1);       // keys [nb*64, nb*64+64)
  __syncthreads();
  scoreStep(&sc[4]);
  __syncthreads();
  stageK(0, 64);            // landmarks at 64*l
  __syncthreads();
  scoreStep(&slm[0]);
  __syncthreads();

  // softmax in registers (row lives across the 16 lanes of a quad group)
  float invL[4], invG[4];
#pragma unroll
  for (int r = 0; r < 4; r++) {
    const int i = wid * 16 + quad * 4 + r;  // query index in block
    float mx = -1e30f;
#pragma unroll
    for (int nt = 0; nt < 8; nt++) {
      int j = nt * 16 + l16;
      float s = sc[nt][r] * SCALE;
      if (j < i || j > i + 64) s = -1e30f;
      sc[nt][r] = s;
      mx = fmaxf(mx, s);
    }
#pragma unroll
    for (int m = 1; m <= 8; m <<= 1) mx = fmaxf(mx, __shfl_xor(mx, m, 64));
    float sum = 0.f;
#pragma unroll
    for (int nt = 0; nt < 8; nt++) {
      float e = __expf(sc[nt][r] - mx);
      sc[nt][r] = e;
      sum += e;
    }
#pragma unroll
    for (int m = 1; m <= 8; m <<= 1) sum += __shfl_xor(sum, m, 64);
    invL[r] = 0.7f / sum;

    float mg = -1e30f;
#pragma unroll
    for (int nt = 0; nt < 4; nt++) {
      int l = nt * 16 + l16;
      float s = slm[nt][r] * SCALE;
      if (l > nb) s = -1e30f;
      slm[nt][r] = s;
      mg = fmaxf(mg, s);
    }
#pragma unroll
    for (int m = 1; m <= 8; m <<= 1) mg = fmaxf(mg, __shfl_xor(mg, m, 64));
    float sg = 0.f;
#pragma unroll
    for (int nt = 0; nt < 4; nt++) {
      float e = __expf(slm[nt][r] - mg);
      slm[nt][r] = e;
      sg += e;
    }
#pragma unroll
    for (int m = 1; m <= 8; m <<= 1) sg += __shfl_xor(sg, m, 64);
    invG[r] = 0.3f / sg;
  }

  // write P (unnormalized exp) into Qs, PL into PLs; stage Vt chunk 0
#pragma unroll
  for (int nt = 0; nt < 8; nt++)
#pragma unroll
    for (int r = 0; r < 4; r++)
      Qs[(wid * 16 + quad * 4 + r) * 136 + nt * 16 + l16] =
          __float2bfloat16(sc[nt][r]);
#pragma unroll
  for (int nt = 0; nt < 4; nt++)
#pragma unroll
    for (int r = 0; r < 4; r++)
      PLs[(wid * 16 + quad * 4 + r) * 72 + nt * 16 + l16] =
          __float2bfloat16(slm[nt][r]);
  stageVt(nb * 64 - 64, 1);
  __syncthreads();

  f32x4 accO[8] = {};
  f32x4 accG[8] = {};
  auto pvStep = [&](f32x4* dst, const bf16* Pbase, int pstride, int colbase) {
#pragma unroll
    for (int kk = 0; kk < 64; kk += 32) {
      bf16x8 a = *(const bf16x8*)(&Pbase[(wid * 16 + l16) * pstride + colbase +
                                         kk + quad * 8]);
#pragma unroll
      for (int nt = 0; nt < 8; nt++) {
        bf16x8 b = *(const bf16x8*)(&kvb[(nt * 16 + l16) * 72 + kk + quad * 8]);
        dst[nt] = __builtin_amdgcn_mfma_f32_16x16x32_bf16(a, b, dst[nt], 0, 0, 0);
      }
    }
  };
  pvStep(accO, Qs, 136, 0);
  __syncthreads();
  stageVt(nb * 64, 1);
  __syncthreads();
  pvStep(accO, Qs, 136, 64);
  __syncthreads();
  stageVt(0, 64);  // LVt
  __syncthreads();
  pvStep(accG, PLs, 72, 0);

#pragma unroll
  for (int nt = 0; nt < 8; nt++)
#pragma unroll
    for (int r = 0; r < 4; r++) {
      int q = nb * 64 + wid * 16 + quad * 4 + r;
      int d = nt * 16 + l16;
      float v = accO[nt][r] * invL[r] + accG[nt][r] * invG[r];
      O[((size_t)q * NH + h) * DH + d] = __float2bfloat16(v);
    }
}

// ---------------- launch ----------------
extern "C" void kernel_launch(void* const* d_in, const int* in_sizes, int n_in,
                              void* d_out, int out_size, void* d_ws,
                              size_t ws_size, hipStream_t stream) {
  const void* X  = d_in[0];
  const void* wq = d_in[1];
  const void* wk = d_in[2];
  const void* wv = d_in[3];
  const void* wo = d_in[4];

  char* ws = (char*)d_ws;
  int* flag = (int*)ws;
  bf16* Qb = (bf16*)(ws + 256);                       // 32 MB
  bf16* Kb = Qb + (size_t)S_LEN * HIDN;               // 8 MB
  bf16* Vb = Kb + (size_t)S_LEN * 1024;               // 8 MB
  bf16* At = Vb + (size_t)S_LEN * 1024;               // 32 MB

  k_detect<<<1, 256, 0, stream>>>((const unsigned short*)wq, flag);

  k_gemm<<<dim3(S_LEN / 128, HIDN / 128), 256, 0, stream>>>(
      X, wq, Qb, flag, S_LEN, HIDN, HIDN, 1, 1, 0);
  k_gemm<<<dim3(S_LEN / 128, 1024 / 128), 256, 0, stream>>>(
      X, wk, Kb, flag, S_LEN, 1024, HIDN, 1, 1, 0);
  k_gemm<<<dim3(S_LEN / 128, 1024 / 128), 256, 0, stream>>>(
      X, wv, Vb, flag, S_LEN, 1024, HIDN, 1, 1, 0);

  k_rope<<<(S_LEN * NH * 64) / 256, 256, 0, stream>>>(Qb, NH, S_LEN * NH * 64);
  k_rope<<<(S_LEN * NKV * 64) / 256, 256, 0, stream>>>(Kb, NKV, S_LEN * NKV * 64);

  k_attn<<<dim3(NBLK, NH), 256, 0, stream>>>(Qb, Kb, Vb, At);

  k_gemm<<<dim3(S_LEN / 128, HIDN / 128), 256, 0, stream>>>(
      At, wo, d_out, flag, S_LEN, HIDN, HIDN, 0, 1, 1);
}

// Round 3
// 913.306 us; speedup vs baseline: 2.3050x; 2.3050x over previous
//
#include <hip/hip_runtime.h>
#include <hip/hip_bf16.h>

// SSA attention, B=1 S=4096 HID=4096 H=32 KV=8 D=128, fp32 in (detected),
// fp32 out. R3: pre-convert/transpose to bf16, m97-style GEMM with
// global_load_lds width-16 staging (874 TF ladder structure).

typedef short bf16x8 __attribute__((ext_vector_type(8)));
typedef float f32x4 __attribute__((ext_vector_type(4)));
using bf16 = __hip_bfloat16;

#define S_LEN 4096
#define HIDN  4096
#define NH    32
#define NKV   8
#define DH    128
#define NBLK  64
#define SCALE 0.08838834764831845f

__device__ __forceinline__ void gload16(const bf16* g, bf16* l) {
  __builtin_amdgcn_global_load_lds(
      (const __attribute__((address_space(1))) unsigned int*)g,
      (__attribute__((address_space(3))) unsigned int*)l, 16, 0, 0);
}

// ---------------- dtype detector (fp32 vs bf16 inputs) ----------------
__global__ void k_detect(const unsigned short* __restrict__ w,
                         int* __restrict__ flag) {
  int t = threadIdx.x;
  unsigned short u = w[t];
  int e = (u >> 7) & 0xFF;
  int bad = (e >= 134) ? 1 : 0;
  __shared__ int cnt;
  if (t == 0) cnt = 0;
  __syncthreads();
  atomicAdd(&cnt, bad);
  __syncthreads();
  if (t == 0) flag[0] = (cnt > 32) ? 1 : 0;
}

// ---------------- convert (no transpose): in -> bf16 out ----------------
__global__ void k_cvt(const void* __restrict__ in, bf16* __restrict__ out,
                      const int* __restrict__ flagp, int n8) {
  int i = blockIdx.x * blockDim.x + threadIdx.x;
  if (i >= n8) return;
  if (*flagp) {
    const float4* p = (const float4*)in + (size_t)i * 2;
    float4 a = p[0], b = p[1];
    alignas(16) bf16 v[8] = {__float2bfloat16(a.x), __float2bfloat16(a.y),
                             __float2bfloat16(a.z), __float2bfloat16(a.w),
                             __float2bfloat16(b.x), __float2bfloat16(b.y),
                             __float2bfloat16(b.z), __float2bfloat16(b.w)};
    *(uint4*)(out + (size_t)i * 8) = *(const uint4*)v;
  } else {
    ((uint4*)out)[i] = ((const uint4*)in)[i];
  }
}

// ------------- transpose+convert: w [K][N] -> wt bf16 [N][K] -------------
__global__ void k_tcvt(const void* __restrict__ w_, bf16* __restrict__ wt,
                       const int* __restrict__ flagp, int K, int N) {
  __shared__ bf16 tile[32][33];
  const bool f32 = *flagp != 0;
  int k0 = blockIdx.x * 32, n0 = blockIdx.y * 32;
  int tx = threadIdx.x, ty = threadIdx.y;  // blockDim (32,8)
#pragma unroll
  for (int i = 0; i < 4; i++) {
    int k = k0 + ty + i * 8;
    bf16 v;
    if (f32)
      v = __float2bfloat16(((const float*)w_)[(size_t)k * N + n0 + tx]);
    else
      v = ((const bf16*)w_)[(size_t)k * N + n0 + tx];
    tile[ty + i * 8][tx] = v;
  }
  __syncthreads();
#pragma unroll
  for (int i = 0; i < 4; i++)
    wt[(size_t)(n0 + ty + i * 8) * K + k0 + tx] = tile[tx][ty + i * 8];
}

// -------- GEMM (m97): C[M][N] = A[M][K] * BT[N][K]^T, all bf16 ----------
__global__ __launch_bounds__(256) void k_gemm(
    const bf16* __restrict__ A, const bf16* __restrict__ BT,
    void* __restrict__ C_, const int* __restrict__ flagp,
    int M, int N, int K, int outMode) {
  __shared__ bf16 Al[128 * 64];
  __shared__ bf16 Bl[128 * 64];
  const int m0 = blockIdx.x * 128, n0 = blockIdx.y * 128;
  const int t = threadIdx.x;
  const int wid = t >> 6, lane = t & 63, quad = lane >> 4, l16 = lane & 15;
  const int wr = (wid >> 1) * 64, wc = (wid & 1) * 64;
  const int srow = wid * 32 + (lane >> 3);  // +p*8
  const int skof = (lane & 7) * 8;
  f32x4 acc[4][4] = {};

  for (int kb = 0; kb < K; kb += 64) {
    // stage A,B tiles [128 rows][64 k] via global_load_lds width 16.
    // lane i of a wave -> LDS base + i*16B (rows of 64 bf16 = 128B = 8 lanes)
#pragma unroll
    for (int p = 0; p < 4; p++) {
      int row = srow + p * 8;
      gload16(A + (size_t)(m0 + row) * K + kb + skof, Al + row * 64 + skof);
      gload16(BT + (size_t)(n0 + row) * K + kb + skof, Bl + row * 64 + skof);
    }
    __syncthreads();
#pragma unroll
    for (int kk = 0; kk < 64; kk += 32) {
      bf16x8 af[4], bfr[4];
#pragma unroll
      for (int i = 0; i < 4; i++)
        af[i] = *(const bf16x8*)(&Al[(wr + i * 16 + l16) * 64 + kk + quad * 8]);
#pragma unroll
      for (int i = 0; i < 4; i++)
        bfr[i] = *(const bf16x8*)(&Bl[(wc + i * 16 + l16) * 64 + kk + quad * 8]);
#pragma unroll
      for (int mt = 0; mt < 4; mt++)
#pragma unroll
        for (int nt = 0; nt < 4; nt++)
          acc[mt][nt] = __builtin_amdgcn_mfma_f32_16x16x32_bf16(
              af[mt], bfr[nt], acc[mt][nt], 0, 0, 0);
    }
    __syncthreads();
  }
  const bool storeF32 = outMode && (*flagp != 0);
#pragma unroll
  for (int mt = 0; mt < 4; mt++)
#pragma unroll
    for (int nt = 0; nt < 4; nt++)
#pragma unroll
      for (int r = 0; r < 4; r++) {
        int m = m0 + wr + mt * 16 + quad * 4 + r;
        int n = n0 + wc + nt * 16 + l16;
        float v = acc[mt][nt][r];
        if (storeF32)
          ((float*)C_)[(size_t)m * N + n] = v;
        else
          ((bf16*)C_)[(size_t)m * N + n] = __float2bfloat16(v);
      }
}

// ---------------- RoPE in place on [S][nheads*DH] (bf16) ----------------
__global__ void k_rope(bf16* __restrict__ x, int nheads, int total) {
  int idx = blockIdx.x * blockDim.x + threadIdx.x;
  if (idx >= total) return;
  int j = idx & 63;   // freq index
  int sh = idx >> 6;  // s*nheads + head
  int s = sh / nheads;
  float invf = (float)exp(-(double)j * (9.210340371976184 / 64.0));
  float ang = (float)s * invf;
  float sn, cs;
  sincosf(ang, &sn, &cs);
  bf16* p = x + (size_t)sh * DH;
  float x1 = __bfloat162float(p[j]);
  float x2 = __bfloat162float(p[j + 64]);
  p[j]      = __float2bfloat16(x1 * cs - x2 * sn);
  p[j + 64] = __float2bfloat16(x2 * cs + x1 * sn);
}

// ---------------- attention: one block per (query-block nb, head h) ------
// local: causal window [q-64, q] (block-0 zero-pad keys included, score 0)
// landmark: landmarks 0..nb (positions 64*l), separate softmax, 0.7/0.3 mix
__global__ __launch_bounds__(256) void k_attn(const bf16* __restrict__ Q,
                                              const bf16* __restrict__ Kk,
                                              const bf16* __restrict__ V,
                                              bf16* __restrict__ O) {
  const int nb = blockIdx.x;
  const int h = blockIdx.y;
  const int kvh = h >> 2;
  const int t = threadIdx.x;
  const int wid = t >> 6, lane = t & 63, quad = lane >> 4, l16 = lane & 15;

  __shared__ bf16 Qs[64 * 136];   // Q tile; reused as P (exp weights)
  __shared__ bf16 kvb[128 * 136]; // K chunks [64][136] / Vt,LVt [128][72]
  __shared__ bf16 PLs[64 * 72];   // landmark exp weights

  const int srow16 = t >> 4, soff = (t & 15) * 8;

  // stage Q [64][128] -> Qs stride 136
#pragma unroll
  for (int p = 0; p < 4; p++) {
    int row = p * 16 + srow16;
    *(uint4*)(&Qs[row * 136 + soff]) =
        *(const uint4*)(Q + ((size_t)(nb * 64 + row) * NH + h) * DH + soff);
  }

  auto stageK = [&](int basePos, int posStride) {
#pragma unroll
    for (int p = 0; p < 4; p++) {
      int row = p * 16 + srow16;
      int pos = basePos + row * posStride;
      uint4 val = make_uint4(0u, 0u, 0u, 0u);
      if (pos >= 0)
        val = *(const uint4*)(Kk + ((size_t)pos * NKV + kvh) * DH + soff);
      *(uint4*)(&kvb[row * 136 + soff]) = val;
    }
  };

  auto stageVt = [&](int basePos, int posStride) {
#pragma unroll
    for (int p = 0; p < 4; p++) {
      int key = p * 16 + srow16;
      int pos = basePos + key * posStride;
      uint4 tv = make_uint4(0u, 0u, 0u, 0u);
      if (pos >= 0)
        tv = *(const uint4*)(V + ((size_t)pos * NKV + kvh) * DH + soff);
      const bf16* tmp = (const bf16*)&tv;
#pragma unroll
      for (int jj = 0; jj < 8; jj++)
        kvb[(soff + jj) * 72 + key] = tmp[jj];
    }
  };

  f32x4 sc[8] = {};
  f32x4 slm[4] = {};

  auto scoreStep = [&](f32x4* dst) {
#pragma unroll
    for (int kk = 0; kk < 128; kk += 32) {
      bf16x8 a = *(const bf16x8*)(&Qs[(wid * 16 + l16) * 136 + kk + quad * 8]);
#pragma unroll
      for (int nt = 0; nt < 4; nt++) {
        bf16x8 b =
            *(const bf16x8*)(&kvb[(nt * 16 + l16) * 136 + kk + quad * 8]);
        dst[nt] = __builtin_amdgcn_mfma_f32_16x16x32_bf16(a, b, dst[nt], 0, 0, 0);
      }
    }
  };

  stageK(nb * 64 - 64, 1);  // keys [nb*64-64, nb*64)
  __syncthreads();
  scoreStep(&sc[0]);
  __syncthreads();
  stageK(nb * 64, 1);       // keys [nb*64, nb*64+64)
  __syncthreads();
  scoreStep(&sc[4]);
  __syncthreads();
  stageK(0, 64);            // landmarks at 64*l
  __syncthreads();
  scoreStep(&slm[0]);
  __syncthreads();

  // softmax in registers (row lives across the 16 lanes of a quad group)
  float invL[4], invG[4];
#pragma unroll
  for (int r = 0; r < 4; r++) {
    const int i = wid * 16 + quad * 4 + r;  // query index in block
    float mx = -1e30f;
#pragma unroll
    for (int nt = 0; nt < 8; nt++) {
      int j = nt * 16 + l16;
      float s = sc[nt][r] * SCALE;
      if (j < i || j > i + 64) s = -1e30f;
      sc[nt][r] = s;
      mx = fmaxf(mx, s);
    }
#pragma unroll
    for (int m = 1; m <= 8; m <<= 1) mx = fmaxf(mx, __shfl_xor(mx, m, 64));
    float sum = 0.f;
#pragma unroll
    for (int nt = 0; nt < 8; nt++) {
      float e = __expf(sc[nt][r] - mx);
      sc[nt][r] = e;
      sum += e;
    }
#pragma unroll
    for (int m = 1; m <= 8; m <<= 1) sum += __shfl_xor(sum, m, 64);
    invL[r] = 0.7f / sum;

    float mg = -1e30f;
#pragma unroll
    for (int nt = 0; nt < 4; nt++) {
      int l = nt * 16 + l16;
      float s = slm[nt][r] * SCALE;
      if (l > nb) s = -1e30f;
      slm[nt][r] = s;
      mg = fmaxf(mg, s);
    }
#pragma unroll
    for (int m = 1; m <= 8; m <<= 1) mg = fmaxf(mg, __shfl_xor(mg, m, 64));
    float sg = 0.f;
#pragma unroll
    for (int nt = 0; nt < 4; nt++) {
      float e = __expf(slm[nt][r] - mg);
      slm[nt][r] = e;
      sg += e;
    }
#pragma unroll
    for (int m = 1; m <= 8; m <<= 1) sg += __shfl_xor(sg, m, 64);
    invG[r] = 0.3f / sg;
  }

  // write P (unnormalized exp) into Qs, PL into PLs; stage Vt chunk 0
#pragma unroll
  for (int nt = 0; nt < 8; nt++)
#pragma unroll
    for (int r = 0; r < 4; r++)
      Qs[(wid * 16 + quad * 4 + r) * 136 + nt * 16 + l16] =
          __float2bfloat16(sc[nt][r]);
#pragma unroll
  for (int nt = 0; nt < 4; nt++)
#pragma unroll
    for (int r = 0; r < 4; r++)
      PLs[(wid * 16 + quad * 4 + r) * 72 + nt * 16 + l16] =
          __float2bfloat16(slm[nt][r]);
  stageVt(nb * 64 - 64, 1);
  __syncthreads();

  f32x4 accO[8] = {};
  f32x4 accG[8] = {};
  auto pvStep = [&](f32x4* dst, const bf16* Pbase, int pstride, int colbase) {
#pragma unroll
    for (int kk = 0; kk < 64; kk += 32) {
      bf16x8 a = *(const bf16x8*)(&Pbase[(wid * 16 + l16) * pstride + colbase +
                                         kk + quad * 8]);
#pragma unroll
      for (int nt = 0; nt < 8; nt++) {
        bf16x8 b = *(const bf16x8*)(&kvb[(nt * 16 + l16) * 72 + kk + quad * 8]);
        dst[nt] = __builtin_amdgcn_mfma_f32_16x16x32_bf16(a, b, dst[nt], 0, 0, 0);
      }
    }
  };
  pvStep(accO, Qs, 136, 0);
  __syncthreads();
  stageVt(nb * 64, 1);
  __syncthreads();
  pvStep(accO, Qs, 136, 64);
  __syncthreads();
  stageVt(0, 64);  // LVt
  __syncthreads();
  pvStep(accG, PLs, 72, 0);

#pragma unroll
  for (int nt = 0; nt < 8; nt++)
#pragma unroll
    for (int r = 0; r < 4; r++) {
      int q = nb * 64 + wid * 16 + quad * 4 + r;
      int d = nt * 16 + l16;
      float v = accO[nt][r] * invL[r] + accG[nt][r] * invG[r];
      O[((size_t)q * NH + h) * DH + d] = __float2bfloat16(v);
    }
}

// ---------------- launch ----------------
extern "C" void kernel_launch(void* const* d_in, const int* in_sizes, int n_in,
                              void* d_out, int out_size, void* d_ws,
                              size_t ws_size, hipStream_t stream) {
  const void* X  = d_in[0];
  const void* wq = d_in[1];
  const void* wk = d_in[2];
  const void* wv = d_in[3];
  const void* wo = d_in[4];

  char* ws = (char*)d_ws;
  int* flag = (int*)ws;
  bf16* Xb  = (bf16*)(ws + 256);              // 32 MB ; later aliased as At
  bf16* WqT = Xb + (size_t)S_LEN * HIDN;      // 32 MB
  bf16* WkT = WqT + (size_t)HIDN * HIDN;      // 8 MB
  bf16* WvT = WkT + (size_t)1024 * HIDN;      // 8 MB
  bf16* Qb  = WvT + (size_t)1024 * HIDN;      // 32 MB ; later aliased as WoT
  bf16* Kb  = Qb + (size_t)S_LEN * HIDN;      // 8 MB
  bf16* Vb  = Kb + (size_t)S_LEN * 1024;      // 8 MB
  bf16* At  = Xb;                             // alias (X dead after V GEMM)
  bf16* WoT = Qb;                             // alias (Q dead after attn)

  k_detect<<<1, 256, 0, stream>>>((const unsigned short*)wq, flag);

  dim3 tb(32, 8);
  k_cvt<<<(S_LEN * HIDN / 8 + 255) / 256, 256, 0, stream>>>(
      X, Xb, flag, S_LEN * HIDN / 8);
  k_tcvt<<<dim3(HIDN / 32, HIDN / 32), tb, 0, stream>>>(wq, WqT, flag, HIDN, HIDN);
  k_tcvt<<<dim3(HIDN / 32, 1024 / 32), tb, 0, stream>>>(wk, WkT, flag, HIDN, 1024);
  k_tcvt<<<dim3(HIDN / 32, 1024 / 32), tb, 0, stream>>>(wv, WvT, flag, HIDN, 1024);

  k_gemm<<<dim3(S_LEN / 128, HIDN / 128), 256, 0, stream>>>(
      Xb, WqT, Qb, flag, S_LEN, HIDN, HIDN, 0);
  k_gemm<<<dim3(S_LEN / 128, 1024 / 128), 256, 0, stream>>>(
      Xb, WkT, Kb, flag, S_LEN, 1024, HIDN, 0);
  k_gemm<<<dim3(S_LEN / 128, 1024 / 128), 256, 0, stream>>>(
      Xb, WvT, Vb, flag, S_LEN, 1024, HIDN, 0);

  k_rope<<<(S_LEN * NH * 64) / 256, 256, 0, stream>>>(Qb, NH, S_LEN * NH * 64);
  k_rope<<<(S_LEN * NKV * 64) / 256, 256, 0, stream>>>(Kb, NKV, S_LEN * NKV * 64);

  k_attn<<<dim3(NBLK, NH), 256, 0, stream>>>(Qb, Kb, Vb, At);

  // wo transpose into Qb region (Q consumed by attention)
  k_tcvt<<<dim3(HIDN / 32, HIDN / 32), tb, 0, stream>>>(wo, WoT, flag, HIDN, HIDN);

  k_gemm<<<dim3(S_LEN / 128, HIDN / 128), 256, 0, stream>>>(
      At, WoT, d_out, flag, S_LEN, HIDN, HIDN, 1);
}

// Round 4
// 760.107 us; speedup vs baseline: 2.7695x; 1.2015x over previous
//
#include <hip/hip_runtime.h>
#include <hip/hip_bf16.h>

// SSA attention, B=1 S=4096 HID=4096 H=32 KV=8 D=128, fp32 in (detected),
// fp32 out. R4: XOR-swizzled LDS in GEMM (kill bank conflicts), fused QKV
// GEMM (N=6144), vectorized transpose, fused RoPE.

typedef short bf16x8 __attribute__((ext_vector_type(8)));
typedef float f32x4 __attribute__((ext_vector_type(4)));
using bf16 = __hip_bfloat16;

#define S_LEN 4096
#define HIDN  4096
#define NH    32
#define NKV   8
#define DH    128
#define NBLK  64
#define SCALE 0.08838834764831845f

__device__ __forceinline__ void gload16(const bf16* g, bf16* l) {
  __builtin_amdgcn_global_load_lds(
      (const __attribute__((address_space(1))) unsigned int*)g,
      (__attribute__((address_space(3))) unsigned int*)l, 16, 0, 0);
}

// ---------------- dtype detector (fp32 vs bf16 inputs) ----------------
__global__ void k_detect(const unsigned short* __restrict__ w,
                         int* __restrict__ flag) {
  int t = threadIdx.x;
  unsigned short u = w[t];
  int e = (u >> 7) & 0xFF;
  int bad = (e >= 134) ? 1 : 0;
  __shared__ int cnt;
  if (t == 0) cnt = 0;
  __syncthreads();
  atomicAdd(&cnt, bad);
  __syncthreads();
  if (t == 0) flag[0] = (cnt > 32) ? 1 : 0;
}

// ---------------- convert (no transpose): in -> bf16 out ----------------
__global__ void k_cvt(const void* __restrict__ in, bf16* __restrict__ out,
                      const int* __restrict__ flagp, int n8) {
  int i = blockIdx.x * blockDim.x + threadIdx.x;
  if (i >= n8) return;
  if (*flagp) {
    const float4* p = (const float4*)in + (size_t)i * 2;
    float4 a = p[0], b = p[1];
    alignas(16) bf16 v[8] = {__float2bfloat16(a.x), __float2bfloat16(a.y),
                             __float2bfloat16(a.z), __float2bfloat16(a.w),
                             __float2bfloat16(b.x), __float2bfloat16(b.y),
                             __float2bfloat16(b.z), __float2bfloat16(b.w)};
    *(uint4*)(out + (size_t)i * 8) = *(const uint4*)v;
  } else {
    ((uint4*)out)[i] = ((const uint4*)in)[i];
  }
}

// ------ transpose+convert: w [K][N] -> wt bf16 [N][K], 64x64 tiles ------
__global__ __launch_bounds__(256) void k_tcvt(const void* __restrict__ w_,
                                              bf16* __restrict__ wt,
                                              const int* __restrict__ flagp,
                                              int K, int N) {
  __shared__ bf16 tile[64][66];  // [k][n], odd word-stride (33)
  const bool f32 = *flagp != 0;
  const int k0 = blockIdx.x * 64, n0 = blockIdx.y * 64;
  const int t = threadIdx.x;
  const int r = t >> 2, c16 = (t & 3) * 16;
  if (f32) {
    const float* src = (const float*)w_ + (size_t)(k0 + r) * N + n0 + c16;
    float4 a = ((const float4*)src)[0], b = ((const float4*)src)[1];
    float4 c = ((const float4*)src)[2], d = ((const float4*)src)[3];
    bf16* dst = &tile[r][c16];
    dst[0] = __float2bfloat16(a.x);  dst[1] = __float2bfloat16(a.y);
    dst[2] = __float2bfloat16(a.z);  dst[3] = __float2bfloat16(a.w);
    dst[4] = __float2bfloat16(b.x);  dst[5] = __float2bfloat16(b.y);
    dst[6] = __float2bfloat16(b.z);  dst[7] = __float2bfloat16(b.w);
    dst[8] = __float2bfloat16(c.x);  dst[9] = __float2bfloat16(c.y);
    dst[10] = __float2bfloat16(c.z); dst[11] = __float2bfloat16(c.w);
    dst[12] = __float2bfloat16(d.x); dst[13] = __float2bfloat16(d.y);
    dst[14] = __float2bfloat16(d.z); dst[15] = __float2bfloat16(d.w);
  } else {
    const bf16* src = (const bf16*)w_ + (size_t)(k0 + r) * N + n0 + c16;
    uint4 a = ((const uint4*)src)[0], b = ((const uint4*)src)[1];
    *(uint4*)(&tile[r][c16]) = a;
    *(uint4*)(&tile[r][c16 + 8]) = b;
  }
  __syncthreads();
  alignas(16) bf16 v[16];
#pragma unroll
  for (int j = 0; j < 16; j++) v[j] = tile[c16 + j][r];
  bf16* dst = wt + (size_t)(n0 + r) * K + k0 + c16;
  ((uint4*)dst)[0] = ((const uint4*)v)[0];
  ((uint4*)dst)[1] = ((const uint4*)v)[1];
}

// -------- GEMM: C[M][N] = A[M][K] * BT[N][K]^T, bf16, XOR-swizzled LDS ---
// kind 0: QKV routing (bf16; n<4096 -> outQ w4096, <5120 -> outK w1024,
//         else outV w1024).  kind 1: single output, fp32 if *flagp.
__global__ __launch_bounds__(256) void k_gemm(
    const bf16* __restrict__ A, const bf16* __restrict__ BT,
    void* __restrict__ outQ, void* __restrict__ outK, void* __restrict__ outV,
    const int* __restrict__ flagp, int M, int N, int K, int kind) {
  __shared__ bf16 Al[128 * 64];
  __shared__ bf16 Bl[128 * 64];
  const int m0 = blockIdx.x * 128, n0 = blockIdx.y * 128;
  const int t = threadIdx.x;
  const int wid = t >> 6, lane = t & 63, quad = lane >> 4, l16 = lane & 15;
  const int wr = (wid >> 1) * 64, wc = (wid & 1) * 64;
  const int srow = wid * 32 + (lane >> 3);          // +p*8
  // XOR swizzle: lane loads global 16B-block (lane&7)^(lane>>3); LDS dest
  // stays base+lane*16 (global_load_lds requirement). LDS block b of row r
  // then holds global block b^(r&7).
  const int sgof = (((lane & 7) ^ (lane >> 3))) * 8; // global col offset
  const int slof = (lane & 7) * 8;                   // LDS col offset
  f32x4 acc[4][4] = {};

  for (int kb = 0; kb < K; kb += 64) {
#pragma unroll
    for (int p = 0; p < 4; p++) {
      int row = srow + p * 8;
      gload16(A + (size_t)(m0 + row) * K + kb + sgof, Al + row * 64 + slof);
      gload16(BT + (size_t)(n0 + row) * K + kb + sgof, Bl + row * 64 + slof);
    }
    __syncthreads();
#pragma unroll
    for (int kk = 0; kk < 64; kk += 32) {
      bf16x8 af[4], bfr[4];
#pragma unroll
      for (int i = 0; i < 4; i++) {
        int sb = (((kk >> 3) + quad) ^ (l16 & 7)) * 8;
        af[i] = *(const bf16x8*)(&Al[(wr + i * 16 + l16) * 64 + sb]);
        bfr[i] = *(const bf16x8*)(&Bl[(wc + i * 16 + l16) * 64 + sb]);
      }
#pragma unroll
      for (int mt = 0; mt < 4; mt++)
#pragma unroll
        for (int nt = 0; nt < 4; nt++)
          acc[mt][nt] = __builtin_amdgcn_mfma_f32_16x16x32_bf16(
              af[mt], bfr[nt], acc[mt][nt], 0, 0, 0);
    }
    __syncthreads();
  }
  const bool storeF32 = (kind == 1) && (*flagp != 0);
#pragma unroll
  for (int mt = 0; mt < 4; mt++)
#pragma unroll
    for (int nt = 0; nt < 4; nt++)
#pragma unroll
      for (int r = 0; r < 4; r++) {
        int m = m0 + wr + mt * 16 + quad * 4 + r;
        int n = n0 + wc + nt * 16 + l16;
        float v = acc[mt][nt][r];
        if (kind == 1) {
          if (storeF32)
            ((float*)outQ)[(size_t)m * N + n] = v;
          else
            ((bf16*)outQ)[(size_t)m * N + n] = __float2bfloat16(v);
        } else {
          bf16* Co;
          if (n < 4096)
            Co = (bf16*)outQ + (size_t)m * 4096 + n;
          else if (n < 5120)
            Co = (bf16*)outK + (size_t)m * 1024 + (n - 4096);
          else
            Co = (bf16*)outV + (size_t)m * 1024 + (n - 5120);
          *Co = __float2bfloat16(v);
        }
      }
}

// -------- RoPE in place, fused Q+K: x[s][nheads][128], pairs (j, j+64) ---
__global__ void k_rope(bf16* __restrict__ Q, bf16* __restrict__ Kb,
                       int totalQ, int total) {
  int idx = blockIdx.x * blockDim.x + threadIdx.x;
  if (idx >= total) return;
  bf16* x;
  int nheads, li;
  if (idx < totalQ) { x = Q; nheads = NH; li = idx; }
  else { x = Kb; nheads = NKV; li = idx - totalQ; }
  int j = li & 63;   // freq index
  int sh = li >> 6;  // s*nheads + head
  int s = sh / nheads;
  float invf = (float)exp(-(double)j * (9.210340371976184 / 64.0));
  float ang = (float)s * invf;
  float sn, cs;
  sincosf(ang, &sn, &cs);
  bf16* p = x + (size_t)sh * DH;
  float x1 = __bfloat162float(p[j]);
  float x2 = __bfloat162float(p[j + 64]);
  p[j]      = __float2bfloat16(x1 * cs - x2 * sn);
  p[j + 64] = __float2bfloat16(x2 * cs + x1 * sn);
}

// ---------------- attention: one block per (query-block nb, head h) ------
// local: causal window [q-64, q] (block-0 zero-pad keys included, score 0)
// landmark: landmarks 0..nb (positions 64*l), separate softmax, 0.7/0.3 mix
__global__ __launch_bounds__(256) void k_attn(const bf16* __restrict__ Q,
                                              const bf16* __restrict__ Kk,
                                              const bf16* __restrict__ V,
                                              bf16* __restrict__ O) {
  const int nb = blockIdx.x;
  const int h = blockIdx.y;
  const int kvh = h >> 2;
  const int t = threadIdx.x;
  const int wid = t >> 6, lane = t & 63, quad = lane >> 4, l16 = lane & 15;

  __shared__ bf16 Qs[64 * 136];   // Q tile; reused as P (exp weights)
  __shared__ bf16 kvb[128 * 136]; // K chunks [64][136] / Vt,LVt [128][72]
  __shared__ bf16 PLs[64 * 72];   // landmark exp weights

  const int srow16 = t >> 4, soff = (t & 15) * 8;

#pragma unroll
  for (int p = 0; p < 4; p++) {
    int row = p * 16 + srow16;
    *(uint4*)(&Qs[row * 136 + soff]) =
        *(const uint4*)(Q + ((size_t)(nb * 64 + row) * NH + h) * DH + soff);
  }

  auto stageK = [&](int basePos, int posStride) {
#pragma unroll
    for (int p = 0; p < 4; p++) {
      int row = p * 16 + srow16;
      int pos = basePos + row * posStride;
      uint4 val = make_uint4(0u, 0u, 0u, 0u);
      if (pos >= 0)
        val = *(const uint4*)(Kk + ((size_t)pos * NKV + kvh) * DH + soff);
      *(uint4*)(&kvb[row * 136 + soff]) = val;
    }
  };

  auto stageVt = [&](int basePos, int posStride) {
#pragma unroll
    for (int p = 0; p < 4; p++) {
      int key = p * 16 + srow16;
      int pos = basePos + key * posStride;
      uint4 tv = make_uint4(0u, 0u, 0u, 0u);
      if (pos >= 0)
        tv = *(const uint4*)(V + ((size_t)pos * NKV + kvh) * DH + soff);
      const bf16* tmp = (const bf16*)&tv;
#pragma unroll
      for (int jj = 0; jj < 8; jj++)
        kvb[(soff + jj) * 72 + key] = tmp[jj];
    }
  };

  f32x4 sc[8] = {};
  f32x4 slm[4] = {};

  auto scoreStep = [&](f32x4* dst) {
#pragma unroll
    for (int kk = 0; kk < 128; kk += 32) {
      bf16x8 a = *(const bf16x8*)(&Qs[(wid * 16 + l16) * 136 + kk + quad * 8]);
#pragma unroll
      for (int nt = 0; nt < 4; nt++) {
        bf16x8 b =
            *(const bf16x8*)(&kvb[(nt * 16 + l16) * 136 + kk + quad * 8]);
        dst[nt] = __builtin_amdgcn_mfma_f32_16x16x32_bf16(a, b, dst[nt], 0, 0, 0);
      }
    }
  };

  stageK(nb * 64 - 64, 1);
  __syncthreads();
  scoreStep(&sc[0]);
  __syncthreads();
  stageK(nb * 64, 1);
  __syncthreads();
  scoreStep(&sc[4]);
  __syncthreads();
  stageK(0, 64);
  __syncthreads();
  scoreStep(&slm[0]);
  __syncthreads();

  float invL[4], invG[4];
#pragma unroll
  for (int r = 0; r < 4; r++) {
    const int i = wid * 16 + quad * 4 + r;
    float mx = -1e30f;
#pragma unroll
    for (int nt = 0; nt < 8; nt++) {
      int j = nt * 16 + l16;
      float s = sc[nt][r] * SCALE;
      if (j < i || j > i + 64) s = -1e30f;
      sc[nt][r] = s;
      mx = fmaxf(mx, s);
    }
#pragma unroll
    for (int m = 1; m <= 8; m <<= 1) mx = fmaxf(mx, __shfl_xor(mx, m, 64));
    float sum = 0.f;
#pragma unroll
    for (int nt = 0; nt < 8; nt++) {
      float e = __expf(sc[nt][r] - mx);
      sc[nt][r] = e;
      sum += e;
    }
#pragma unroll
    for (int m = 1; m <= 8; m <<= 1) sum += __shfl_xor(sum, m, 64);
    invL[r] = 0.7f / sum;

    float mg = -1e30f;
#pragma unroll
    for (int nt = 0; nt < 4; nt++) {
      int l = nt * 16 + l16;
      float s = slm[nt][r] * SCALE;
      if (l > nb) s = -1e30f;
      slm[nt][r] = s;
      mg = fmaxf(mg, s);
    }
#pragma unroll
    for (int m = 1; m <= 8; m <<= 1) mg = fmaxf(mg, __shfl_xor(mg, m, 64));
    float sg = 0.f;
#pragma unroll
    for (int nt = 0; nt < 4; nt++) {
      float e = __expf(slm[nt][r] - mg);
      slm[nt][r] = e;
      sg += e;
    }
#pragma unroll
    for (int m = 1; m <= 8; m <<= 1) sg += __shfl_xor(sg, m, 64);
    invG[r] = 0.3f / sg;
  }

#pragma unroll
  for (int nt = 0; nt < 8; nt++)
#pragma unroll
    for (int r = 0; r < 4; r++)
      Qs[(wid * 16 + quad * 4 + r) * 136 + nt * 16 + l16] =
          __float2bfloat16(sc[nt][r]);
#pragma unroll
  for (int nt = 0; nt < 4; nt++)
#pragma unroll
    for (int r = 0; r < 4; r++)
      PLs[(wid * 16 + quad * 4 + r) * 72 + nt * 16 + l16] =
          __float2bfloat16(slm[nt][r]);
  stageVt(nb * 64 - 64, 1);
  __syncthreads();

  f32x4 accO[8] = {};
  f32x4 accG[8] = {};
  auto pvStep = [&](f32x4* dst, const bf16* Pbase, int pstride, int colbase) {
#pragma unroll
    for (int kk = 0; kk < 64; kk += 32) {
      bf16x8 a = *(const bf16x8*)(&Pbase[(wid * 16 + l16) * pstride + colbase +
                                         kk + quad * 8]);
#pragma unroll
      for (int nt = 0; nt < 8; nt++) {
        bf16x8 b = *(const bf16x8*)(&kvb[(nt * 16 + l16) * 72 + kk + quad * 8]);
        dst[nt] = __builtin_amdgcn_mfma_f32_16x16x32_bf16(a, b, dst[nt], 0, 0, 0);
      }
    }
  };
  pvStep(accO, Qs, 136, 0);
  __syncthreads();
  stageVt(nb * 64, 1);
  __syncthreads();
  pvStep(accO, Qs, 136, 64);
  __syncthreads();
  stageVt(0, 64);
  __syncthreads();
  pvStep(accG, PLs, 72, 0);

#pragma unroll
  for (int nt = 0; nt < 8; nt++)
#pragma unroll
    for (int r = 0; r < 4; r++) {
      int q = nb * 64 + wid * 16 + quad * 4 + r;
      int d = nt * 16 + l16;
      float v = accO[nt][r] * invL[r] + accG[nt][r] * invG[r];
      O[((size_t)q * NH + h) * DH + d] = __float2bfloat16(v);
    }
}

// ---------------- launch ----------------
extern "C" void kernel_launch(void* const* d_in, const int* in_sizes, int n_in,
                              void* d_out, int out_size, void* d_ws,
                              size_t ws_size, hipStream_t stream) {
  const void* X  = d_in[0];
  const void* wq = d_in[1];
  const void* wk = d_in[2];
  const void* wv = d_in[3];
  const void* wo = d_in[4];

  char* ws = (char*)d_ws;
  int* flag = (int*)ws;
  bf16* Xb   = (bf16*)(ws + 256);               // 32 MB ; aliased as At
  bf16* Wcat = Xb + (size_t)S_LEN * HIDN;       // 48 MB [6144][4096]
  bf16* Qb   = Wcat + (size_t)6144 * HIDN;      // 32 MB
  bf16* Kb   = Qb + (size_t)S_LEN * HIDN;       // 8 MB
  bf16* Vb   = Kb + (size_t)S_LEN * 1024;       // 8 MB
  bf16* At   = Xb;                              // alias (X dead after QKV)
  bf16* WoT  = Wcat;                            // alias (Wcat dead after QKV)

  k_detect<<<1, 256, 0, stream>>>((const unsigned short*)wq, flag);

  k_cvt<<<(S_LEN * HIDN / 8 + 255) / 256, 256, 0, stream>>>(
      X, Xb, flag, S_LEN * HIDN / 8);
  k_tcvt<<<dim3(HIDN / 64, HIDN / 64), 256, 0, stream>>>(
      wq, Wcat, flag, HIDN, HIDN);
  k_tcvt<<<dim3(HIDN / 64, 1024 / 64), 256, 0, stream>>>(
      wk, Wcat + (size_t)4096 * HIDN, flag, HIDN, 1024);
  k_tcvt<<<dim3(HIDN / 64, 1024 / 64), 256, 0, stream>>>(
      wv, Wcat + (size_t)5120 * HIDN, flag, HIDN, 1024);

  // fused QKV GEMM: [4096][4096] x [6144][4096]^T -> Qb|Kb|Vb
  k_gemm<<<dim3(S_LEN / 128, 6144 / 128), 256, 0, stream>>>(
      Xb, Wcat, Qb, Kb, Vb, flag, S_LEN, 6144, HIDN, 0);

  int totalQ = S_LEN * NH * 64, total = totalQ + S_LEN * NKV * 64;
  k_rope<<<(total + 255) / 256, 256, 0, stream>>>(Qb, Kb, totalQ, total);

  k_attn<<<dim3(NBLK, NH), 256, 0, stream>>>(Qb, Kb, Vb, At);

  k_tcvt<<<dim3(HIDN / 64, HIDN / 64), 256, 0, stream>>>(
      wo, WoT, flag, HIDN, HIDN);

  k_gemm<<<dim3(S_LEN / 128, HIDN / 128), 256, 0, stream>>>(
      At, WoT, d_out, nullptr, nullptr, flag, S_LEN, HIDN, HIDN, 1);
}